// Round 1
// baseline (7435.065 us; speedup 1.0000x reference)
//
#include <hip/hip_runtime.h>
#include <math.h>

#define E_TOTAL 200000
#define D 256
#define H 128
#define TE 8   // edges per block

// Transpose (768,256) row-major -> (256,768) row-major so GRU weight reads
// are lane-coalesced: wT[k*768 + o] = w[o*256 + k].
__global__ void transpose_w(const float* __restrict__ w, float* __restrict__ wT) {
    int i = blockIdx.x * 256 + threadIdx.x;
    if (i >= 768 * 256) return;
    int o = i % 768;
    int k = i / 768;
    wT[i] = w[o * 256 + k];
}

__global__ __launch_bounds__(256, 2) void tgn_fused(
    const float* __restrict__ memory, const int* __restrict__ src,
    const int* __restrict__ dst, const float* __restrict__ time_,
    const float* __restrict__ w1, const float* __restrict__ b1,
    const float* __restrict__ w2, const float* __restrict__ b2,
    const float* __restrict__ wihT, const float* __restrict__ whhT,
    const float* __restrict__ b_ih, const float* __restrict__ b_hh,
    const float* __restrict__ p1, const float* __restrict__ pb1,
    const float* __restrict__ p2, const float* __restrict__ pb2,
    float* __restrict__ out_score, float* __restrict__ out_ns,
    float* __restrict__ out_nd)
{
    __shared__ __align__(16) float srcm[TE][D];   // src row; later new_src
    __shared__ __align__(16) float dstm[TE][D];   // dst row; later new_dst
    __shared__ __align__(16) float msg[TE][D];    // message
    __shared__ __align__(16) float hid[TE][H];    // MLP hidden, reused by scorer
    __shared__ float tt[TE];

    const int t = threadIdx.x;
    const int eBase = blockIdx.x * TE;

    // ---- stage gathers: 32 threads per edge, 16B/lane coalesced within a row
    {
        int e = t >> 5;
        int l = t & 31;
        int si = src[eBase + e];
        int di = dst[eBase + e];
        const float4* mrs = (const float4*)(memory + (size_t)si * D);
        const float4* mrd = (const float4*)(memory + (size_t)di * D);
        float4* s4 = (float4*)&srcm[e][0];
        float4* d4 = (float4*)&dstm[e][0];
        s4[l]      = mrs[l];
        s4[l + 32] = mrs[l + 32];
        d4[l]      = mrd[l];
        d4[l + 32] = mrd[l + 32];
        if (t < TE) tt[t] = time_[eBase + t];
    }
    __syncthreads();

    // ---- hidden = relu(msg_in @ w1 + b1); msg_in = [src | dst | t]  (K=513)
    {
        int o = t & 127;
        int eh = t >> 7;            // 2 halves x 4 edges
        float acc[4] = {0.f, 0.f, 0.f, 0.f};
        for (int k0 = 0; k0 < 512; k0 += 4) {
            float wv[4];
            #pragma unroll
            for (int j = 0; j < 4; j++) wv[j] = w1[(k0 + j) * H + o];
            #pragma unroll
            for (int ei = 0; ei < 4; ei++) {
                int e = eh * 4 + ei;
                float4 a = (k0 < 256) ? ((const float4*)srcm[e])[k0 >> 2]
                                      : ((const float4*)dstm[e])[(k0 - 256) >> 2];
                acc[ei] += a.x * wv[0] + a.y * wv[1] + a.z * wv[2] + a.w * wv[3];
            }
        }
        float wlast = w1[512 * H + o];
        float bb = b1[o];
        #pragma unroll
        for (int ei = 0; ei < 4; ei++) {
            int e = eh * 4 + ei;
            hid[e][o] = fmaxf(acc[ei] + tt[e] * wlast + bb, 0.f);
        }
    }
    __syncthreads();

    // ---- message = hid @ w2 + b2   (K=128, out D=256)
    {
        int o = t;                  // 0..255
        float acc[TE];
        #pragma unroll
        for (int e = 0; e < TE; e++) acc[e] = 0.f;
        for (int k0 = 0; k0 < H; k0 += 4) {
            float wv[4];
            #pragma unroll
            for (int j = 0; j < 4; j++) wv[j] = w2[(k0 + j) * D + o];
            #pragma unroll
            for (int e = 0; e < TE; e++) {
                float4 a = ((const float4*)hid[e])[k0 >> 2];
                acc[e] += a.x * wv[0] + a.y * wv[1] + a.z * wv[2] + a.w * wv[3];
            }
        }
        float bb = b2[o];
        #pragma unroll
        for (int e = 0; e < TE; e++) msg[e][o] = acc[e] + bb;
    }
    __syncthreads();

    // ---- GRU: thread t owns feature d=t of all 3 gates x {gi, gh_src, gh_dst}
    {
        int d = t;
        float gi[TE][3], ghs[TE][3], ghd[TE][3];
        #pragma unroll
        for (int e = 0; e < TE; e++)
            #pragma unroll
            for (int g = 0; g < 3; g++) { gi[e][g] = 0.f; ghs[e][g] = 0.f; ghd[e][g] = 0.f; }

        for (int k0 = 0; k0 < D; k0 += 4) {
            float wi[3][4], wh[3][4];
            #pragma unroll
            for (int g = 0; g < 3; g++) {
                #pragma unroll
                for (int j = 0; j < 4; j++) {
                    wi[g][j] = wihT[(size_t)(k0 + j) * 768 + g * 256 + d];
                    wh[g][j] = whhT[(size_t)(k0 + j) * 768 + g * 256 + d];
                }
            }
            #pragma unroll
            for (int e = 0; e < TE; e++) {
                float4 am = ((const float4*)msg[e])[k0 >> 2];
                float4 as = ((const float4*)srcm[e])[k0 >> 2];
                float4 ad = ((const float4*)dstm[e])[k0 >> 2];
                #pragma unroll
                for (int g = 0; g < 3; g++) {
                    gi[e][g]  += am.x * wi[g][0] + am.y * wi[g][1] + am.z * wi[g][2] + am.w * wi[g][3];
                    ghs[e][g] += as.x * wh[g][0] + as.y * wh[g][1] + as.z * wh[g][2] + as.w * wh[g][3];
                    ghd[e][g] += ad.x * wh[g][0] + ad.y * wh[g][1] + ad.z * wh[g][2] + ad.w * wh[g][3];
                }
            }
        }
        float bi0 = b_ih[d], bi1 = b_ih[256 + d], bi2 = b_ih[512 + d];
        float bh0 = b_hh[d], bh1 = b_hh[256 + d], bh2 = b_hh[512 + d];
        __syncthreads();   // everyone done reading srcm/dstm/msg via broadcast
        #pragma unroll
        for (int e = 0; e < TE; e++) {
            float ir = gi[e][0] + bi0, iz = gi[e][1] + bi1, in_ = gi[e][2] + bi2;
            // src cell
            float hr = ghs[e][0] + bh0, hz = ghs[e][1] + bh1, hn = ghs[e][2] + bh2;
            float r = 1.f / (1.f + __expf(-(ir + hr)));
            float z = 1.f / (1.f + __expf(-(iz + hz)));
            float n = tanhf(in_ + r * hn);
            float hs = srcm[e][d];
            float ns = (1.f - z) * n + z * hs;
            // dst cell
            hr = ghd[e][0] + bh0; hz = ghd[e][1] + bh1; hn = ghd[e][2] + bh2;
            r = 1.f / (1.f + __expf(-(ir + hr)));
            z = 1.f / (1.f + __expf(-(iz + hz)));
            n = tanhf(in_ + r * hn);
            float hd = dstm[e][d];
            float nd = (1.f - z) * n + z * hd;
            srcm[e][d] = ns;            // only thread d touches [e][d] here
            dstm[e][d] = nd;
            out_ns[(size_t)(eBase + e) * D + d] = ns;
            out_nd[(size_t)(eBase + e) * D + d] = nd;
        }
    }
    __syncthreads();

    // ---- scorer hidden = relu([new_src | new_dst] @ p1 + pb1)   (K=512)
    {
        int o = t & 127;
        int eh = t >> 7;
        float acc[4] = {0.f, 0.f, 0.f, 0.f};
        for (int k0 = 0; k0 < D; k0 += 4) {
            float wv[4];
            #pragma unroll
            for (int j = 0; j < 4; j++) wv[j] = p1[(k0 + j) * H + o];
            #pragma unroll
            for (int ei = 0; ei < 4; ei++) {
                int e = eh * 4 + ei;
                float4 a = ((const float4*)srcm[e])[k0 >> 2];
                acc[ei] += a.x * wv[0] + a.y * wv[1] + a.z * wv[2] + a.w * wv[3];
            }
        }
        for (int k0 = 0; k0 < D; k0 += 4) {
            float wv[4];
            #pragma unroll
            for (int j = 0; j < 4; j++) wv[j] = p1[(256 + k0 + j) * H + o];
            #pragma unroll
            for (int ei = 0; ei < 4; ei++) {
                int e = eh * 4 + ei;
                float4 a = ((const float4*)dstm[e])[k0 >> 2];
                acc[ei] += a.x * wv[0] + a.y * wv[1] + a.z * wv[2] + a.w * wv[3];
            }
        }
        float bb = pb1[o];
        #pragma unroll
        for (int ei = 0; ei < 4; ei++) {
            int e = eh * 4 + ei;
            hid[e][o] = fmaxf(acc[ei] + bb, 0.f);
        }
    }
    __syncthreads();

    // ---- score = hid @ p2 + pb2 : 32 lanes per edge, shuffle-reduce
    {
        int e = t >> 5;
        int l = t & 31;
        float4 a = ((const float4*)hid[e])[l];
        float4 p = ((const float4*)p2)[l];
        float v = a.x * p.x + a.y * p.y + a.z * p.z + a.w * p.w;
        v += __shfl_down(v, 16, 32);
        v += __shfl_down(v, 8, 32);
        v += __shfl_down(v, 4, 32);
        v += __shfl_down(v, 2, 32);
        v += __shfl_down(v, 1, 32);
        if (l == 0) out_score[eBase + e] = v + pb2[0];
    }
}

extern "C" void kernel_launch(void* const* d_in, const int* in_sizes, int n_in,
                              void* d_out, int out_size, void* d_ws, size_t ws_size,
                              hipStream_t stream) {
    const float* memory = (const float*)d_in[0];
    const int*   src    = (const int*)d_in[1];
    const int*   dst    = (const int*)d_in[2];
    const float* time_  = (const float*)d_in[3];
    const float* w1     = (const float*)d_in[4];
    const float* b1     = (const float*)d_in[5];
    const float* w2     = (const float*)d_in[6];
    const float* b2     = (const float*)d_in[7];
    const float* w_ih   = (const float*)d_in[8];
    const float* w_hh   = (const float*)d_in[9];
    const float* b_ih   = (const float*)d_in[10];
    const float* b_hh   = (const float*)d_in[11];
    const float* p1     = (const float*)d_in[12];
    const float* pb1    = (const float*)d_in[13];
    const float* p2     = (const float*)d_in[14];
    const float* pb2    = (const float*)d_in[15];

    float* out = (float*)d_out;
    float* out_score = out;                                   // (E,1)
    float* out_ns    = out + E_TOTAL;                         // (E,256)
    float* out_nd    = out + E_TOTAL + (size_t)E_TOTAL * D;   // (E,256)

    float* wihT = (float*)d_ws;            // 256x768 f32
    float* whhT = wihT + 768 * 256;        // 256x768 f32

    const int nT = 768 * 256;
    transpose_w<<<(nT + 255) / 256, 256, 0, stream>>>(w_ih, wihT);
    transpose_w<<<(nT + 255) / 256, 256, 0, stream>>>(w_hh, whhT);
    tgn_fused<<<E_TOTAL / TE, 256, 0, stream>>>(
        memory, src, dst, time_, w1, b1, w2, b2, wihT, whhT, b_ih, b_hh,
        p1, pb1, p2, pb2, out_score, out_ns, out_nd);
}